// Round 6
// baseline (244.521 us; speedup 1.0000x reference)
//
#include <hip/hip_runtime.h>
#include <math.h>

#define NN 20000
#define KK 16
#define DD 256
#define VV 64
#define NT1 16
#define SAS 352  // sA row stride in shorts (320 data + 32 pad)

typedef __attribute__((ext_vector_type(8))) __bf16 bf16x8;
typedef __attribute__((ext_vector_type(4))) float floatx4;
typedef __attribute__((ext_vector_type(2))) float floatx2;
typedef __attribute__((ext_vector_type(8))) unsigned short ushort8;

__device__ __forceinline__ float4 ld4(const float* p) { return *reinterpret_cast<const float4*>(p); }

__device__ __forceinline__ unsigned short f2bf(float f) {
    union { float f; unsigned u; } v; v.f = f;
    unsigned r = v.u + 0x7FFFu + ((v.u >> 16) & 1u);
    return (unsigned short)(r >> 16);
}
__device__ __forceinline__ float bf2f(unsigned short u) {
    union { unsigned u; float f; } v; v.u = ((unsigned)u) << 16;
    return v.f;
}
__device__ __forceinline__ unsigned char f2q(float f) {  // fp8 e4m3, RTNE
    return (unsigned char)(__builtin_amdgcn_cvt_pk_fp8_f32(f, 0.f, 0u, false) & 0xFFu);
}
__device__ __forceinline__ float q2f(unsigned char q) {
    floatx2 r = __builtin_amdgcn_cvt_pk_f32_fp8((unsigned)q, false);
    return r.x;
}
__device__ __forceinline__ float ftanh(float v) {
    float e = __expf(2.f * v);
    return 1.f - 2.f * __builtin_amdgcn_rcpf(e + 1.f);
}

// EW[layer][v][d] = sum_j emb_l[v][j] * W_l[256+j][d]
__global__ __launch_bounds__(256) void ewk3(const float* __restrict__ e1, const float* __restrict__ W1,
                                            const float* __restrict__ e2, const float* __restrict__ W2,
                                            const float* __restrict__ e3, const float* __restrict__ W3,
                                            float* __restrict__ EW) {
    int layer = blockIdx.y;
    const float* emb = layer == 0 ? e1 : (layer == 1 ? e2 : e3);
    const float* W   = layer == 0 ? W1 : (layer == 1 ? W2 : W3);
    int v = blockIdx.x, d = threadIdx.x;
    float acc = 0.f;
    #pragma unroll 8
    for (int j = 0; j < 256; ++j)
        acc += emb[v * DD + j] * W[(size_t)(256 + j) * DD + d];
    EW[(size_t)layer * VV * DD + v * DD + d] = acc;
}

// Pack B = [W_top(256); EW(64)] (K=320) into MFMA B-fragment layout; U1 (16 ntiles) and U23 (32).
__global__ __launch_bounds__(256) void packU2(const float* __restrict__ W1, const float* __restrict__ EW1,
                                              const float* __restrict__ W2, const float* __restrict__ EW2,
                                              const float* __restrict__ W3, const float* __restrict__ EW3,
                                              unsigned short* __restrict__ U1, unsigned short* __restrict__ U23) {
    int blk = blockIdx.x;
    int NT; unsigned short* U; const float *Wa, *EWa, *Wb, *EWb; int g;
    if (blk < 40) { NT = 16; U = U1;  Wa = W1; EWa = EW1; Wb = W1; EWb = EW1; g = blk * 256 + threadIdx.x; }
    else          { NT = 32; U = U23; Wa = W2; EWa = EW2; Wb = W3; EWb = EW3; g = (blk - 40) * 256 + threadIdx.x; }
    int lane = g & 63, ntk = g >> 6;
    int nt = ntk % NT, kt = ntk / NT;
    if (kt >= 10) return;
    int n = nt * 16 + (lane & 15);
    int kbase = kt * 32 + (lane >> 4) * 8;
    const float* W = Wa; const float* EW = EWa;
    if (n >= 256) { W = Wb; EW = EWb; n -= 256; }
    unsigned short o8[8];
    #pragma unroll
    for (int j = 0; j < 8; ++j) {
        int k = kbase + j;
        float v = (k < 256) ? W[(size_t)k * DD + n] : EW[(size_t)(k - 256) * DD + n];
        o8[j] = f2bf(v);
    }
    *reinterpret_cast<uint4*>(&U[(size_t)g * 8]) = *reinterpret_cast<uint4*>(o8);
}

// Masked edge histogram -> compact Hc[n][64] bf16; plus x -> bf16 cast (xh).
__global__ __launch_bounds__(256) void prep(const int* __restrict__ ie, const float* __restrict__ im,
                                            const int* __restrict__ oe, const float* __restrict__ om,
                                            const float* __restrict__ x,
                                            unsigned short* __restrict__ Hc, unsigned short* __restrict__ xh) {
    int w = threadIdx.x >> 6, lane = threadIdx.x & 63;
    int n = blockIdx.x * 4 + w;
    int e = 0; float m = 0.f;
    if (lane < 16)      { e = ie[n * KK + lane];      m = im[n * KK + lane]; }
    else if (lane < 32) { e = oe[n * KK + lane - 16]; m = om[n * KK + lane - 16]; }
    float h = 0.f;
    #pragma unroll
    for (int j = 0; j < 32; ++j) {
        int ev = __shfl(e, j);
        float mv = __shfl(m, j);
        if (ev == lane) h += mv;
    }
    Hc[(size_t)n * 64 + lane] = f2bf(h);
    size_t base = (size_t)blockIdx.x * 1024 + threadIdx.x * 4;
    float4 v = ld4(x + base);
    ushort4 o; o.x = f2bf(v.x); o.y = f2bf(v.y); o.z = f2bf(v.z); o.w = f2bf(v.w);
    *reinterpret_cast<ushort4*>(xh + base) = o;
}

// Fused pass 1: per-thread (row, 16-col chunk) bf16 gather into LDS A-tile (max MLP,
// no shuffles), then hidden = x + 2*b1 + [S1|H] @ U1. Writes f32 out + fp8 copy.
__global__ __launch_bounds__(256, 4) void fmm1(const unsigned short* __restrict__ xh, const unsigned short* __restrict__ Hc,
                                               const int* __restrict__ ii, const float* __restrict__ im,
                                               const int* __restrict__ oi, const float* __restrict__ om,
                                               const unsigned short* __restrict__ U, const float* __restrict__ b,
                                               float* __restrict__ out, unsigned char* __restrict__ h8) {
    __shared__ unsigned short sA[16 * SAS];
    __shared__ int sidx[16][32];
    __shared__ float smsk[16][32];
    int n0 = blockIdx.x * 16;
    int tid = threadIdx.x;
    for (int q = tid; q < 512; q += 256) {
        int r = q >> 5, j = q & 31;
        int n = n0 + r;
        sidx[r][j] = (j < 16) ? ii[n * KK + j] : oi[n * KK + j - 16];
        smsk[r][j] = (j < 16) ? im[n * KK + j] : om[n * KK + j - 16];
    }
    if (tid < 128) {  // stage H cols [256,320)
        int r = tid >> 3, k8 = tid & 7;
        *reinterpret_cast<uint4*>(&sA[r * SAS + 256 + k8 * 8]) =
            *reinterpret_cast<const uint4*>(&Hc[(size_t)(n0 + r) * 64 + k8 * 8]);
    }
    int lane = tid & 63, w = tid >> 6;
    int lr = lane & 15, quad = lane >> 4;
    // prefetch epilogue operands (xh/b are ready now; latency hidden behind gather+MFMA)
    float xp[4][4], bb[4];
    #pragma unroll
    for (int t = 0; t < 4; ++t) {
        int col = (w * 4 + t) * 16 + lr;
        bb[t] = 2.f * b[col];
        #pragma unroll
        for (int r = 0; r < 4; ++r)
            xp[t][r] = bf2f(xh[(size_t)(n0 + quad * 4 + r) * DD + col]);
    }
    __syncthreads();
    // gather: thread owns (gr, cols gc*16..gc*16+15); 64 independent 16B loads
    {
        int gr = tid >> 4, gc = tid & 15;
        float acc[16];
        #pragma unroll
        for (int z = 0; z < 16; ++z) acc[z] = 0.f;
        const unsigned short* basecol = xh + gc * 16;
        #pragma unroll 8
        for (int j = 0; j < 32; ++j) {
            int idx = sidx[gr][j];
            float m = smsk[gr][j];
            const unsigned short* p = basecol + (size_t)idx * DD;
            ushort8 u0 = *reinterpret_cast<const ushort8*>(p);
            ushort8 u1 = *reinterpret_cast<const ushort8*>(p + 8);
            #pragma unroll
            for (int z = 0; z < 8; ++z) {
                acc[z]     += m * bf2f(u0[z]);
                acc[z + 8] += m * bf2f(u1[z]);
            }
        }
        unsigned short o16[16];
        #pragma unroll
        for (int z = 0; z < 16; ++z) o16[z] = f2bf(acc[z]);
        uint4* dst = reinterpret_cast<uint4*>(&sA[gr * SAS + gc * 16]);
        dst[0] = reinterpret_cast<uint4*>(o16)[0];
        dst[1] = reinterpret_cast<uint4*>(o16)[1];
    }
    __syncthreads();
    floatx4 z = {0.f, 0.f, 0.f, 0.f};
    floatx4 acc[4] = {z, z, z, z};
    for (int kt = 0; kt < 10; ++kt) {
        bf16x8 a = *reinterpret_cast<const bf16x8*>(&sA[lr * SAS + kt * 32 + quad * 8]);
        #pragma unroll
        for (int t = 0; t < 4; ++t) {
            bf16x8 bf = *reinterpret_cast<const bf16x8*>(&U[(size_t)((kt * NT1 + w * 4 + t) * 64 + lane) * 8]);
            acc[t] = __builtin_amdgcn_mfma_f32_16x16x32_bf16(a, bf, acc[t], 0, 0, 0);
        }
    }
    #pragma unroll
    for (int t = 0; t < 4; ++t) {
        int col = (w * 4 + t) * 16 + lr;
        #pragma unroll
        for (int r = 0; r < 4; ++r) {
            size_t o = (size_t)(n0 + quad * 4 + r) * DD + col;
            float v = xp[t][r] + bb[t] + acc[t][r];
            out[o] = v;
            h8[o] = f2q(v);
        }
    }
}

// Fused pass 2: per-thread (row, 16-col chunk) fp8 gather into LDS A-tile, then BOTH
// mu and logvar matmuls + fast tanh + separable KLD partial.
__global__ __launch_bounds__(256, 4) void fmm23(const unsigned char* __restrict__ h8, const unsigned short* __restrict__ Hc,
                                                const int* __restrict__ ii, const float* __restrict__ im,
                                                const int* __restrict__ oi, const float* __restrict__ om,
                                                const unsigned short* __restrict__ U, const float* __restrict__ b2,
                                                const float* __restrict__ b3, float* __restrict__ partials) {
    __shared__ unsigned short sA[16 * SAS];
    __shared__ int sidx[16][32];
    __shared__ float smsk[16][32];
    __shared__ float red[4];
    int n0 = blockIdx.x * 16;
    int tid = threadIdx.x;
    for (int q = tid; q < 512; q += 256) {
        int r = q >> 5, j = q & 31;
        int n = n0 + r;
        sidx[r][j] = (j < 16) ? ii[n * KK + j] : oi[n * KK + j - 16];
        smsk[r][j] = (j < 16) ? im[n * KK + j] : om[n * KK + j - 16];
    }
    if (tid < 128) {
        int r = tid >> 3, k8 = tid & 7;
        *reinterpret_cast<uint4*>(&sA[r * SAS + 256 + k8 * 8]) =
            *reinterpret_cast<const uint4*>(&Hc[(size_t)(n0 + r) * 64 + k8 * 8]);
    }
    int lane = tid & 63, w = tid >> 6;
    int lr = lane & 15, quad = lane >> 4;
    // prefetch epilogue operands (h8 diag + biases are ready now)
    float hp[4][4], bm[4], bl[4];
    #pragma unroll
    for (int t = 0; t < 4; ++t) {
        int col = (w * 4 + t) * 16 + lr;
        bm[t] = 2.f * b2[col];
        bl[t] = 2.f * b3[col];
        #pragma unroll
        for (int r = 0; r < 4; ++r)
            hp[t][r] = q2f(h8[(size_t)(n0 + quad * 4 + r) * DD + col]);
    }
    __syncthreads();
    // gather: 32 independent uint4 loads per thread
    {
        int gr = tid >> 4, gc = tid & 15;
        float acc[16];
        #pragma unroll
        for (int z = 0; z < 16; ++z) acc[z] = 0.f;
        const unsigned char* basecol = h8 + gc * 16;
        #pragma unroll 8
        for (int j = 0; j < 32; ++j) {
            int idx = sidx[gr][j];
            float m = smsk[gr][j];
            uint4 u = *reinterpret_cast<const uint4*>(basecol + (size_t)idx * DD);
            unsigned dw[4] = {u.x, u.y, u.z, u.w};
            #pragma unroll
            for (int d = 0; d < 4; ++d) {
                floatx2 f01 = __builtin_amdgcn_cvt_pk_f32_fp8(dw[d], false);
                floatx2 f23 = __builtin_amdgcn_cvt_pk_f32_fp8(dw[d], true);
                acc[d * 4 + 0] += m * f01.x; acc[d * 4 + 1] += m * f01.y;
                acc[d * 4 + 2] += m * f23.x; acc[d * 4 + 3] += m * f23.y;
            }
        }
        unsigned short o16[16];
        #pragma unroll
        for (int z = 0; z < 16; ++z) o16[z] = f2bf(acc[z]);
        uint4* dst = reinterpret_cast<uint4*>(&sA[gr * SAS + gc * 16]);
        dst[0] = reinterpret_cast<uint4*>(o16)[0];
        dst[1] = reinterpret_cast<uint4*>(o16)[1];
    }
    __syncthreads();
    floatx4 z = {0.f, 0.f, 0.f, 0.f};
    floatx4 am[4] = {z, z, z, z};
    floatx4 al[4] = {z, z, z, z};
    for (int kt = 0; kt < 10; ++kt) {
        bf16x8 a = *reinterpret_cast<const bf16x8*>(&sA[lr * SAS + kt * 32 + quad * 8]);
        #pragma unroll
        for (int t = 0; t < 4; ++t) {
            int nt = w * 4 + t;
            bf16x8 bmu = *reinterpret_cast<const bf16x8*>(&U[(size_t)((kt * 32 + nt) * 64 + lane) * 8]);
            bf16x8 blv = *reinterpret_cast<const bf16x8*>(&U[(size_t)((kt * 32 + 16 + nt) * 64 + lane) * 8]);
            am[t] = __builtin_amdgcn_mfma_f32_16x16x32_bf16(a, bmu, am[t], 0, 0, 0);
            al[t] = __builtin_amdgcn_mfma_f32_16x16x32_bf16(a, blv, al[t], 0, 0, 0);
        }
    }
    float kacc = 0.f;
    #pragma unroll
    for (int t = 0; t < 4; ++t) {
        #pragma unroll
        for (int r = 0; r < 4; ++r) {
            float h = hp[t][r];
            float tm = ftanh(h + bm[t] + am[t][r]);
            float tl = ftanh(h + bl[t] + al[t][r]);
            kacc += (1.f - tm * tm) + (2.f * tl - __expf(2.f * tl));
        }
    }
    #pragma unroll
    for (int off = 32; off > 0; off >>= 1) kacc += __shfl_xor(kacc, off);
    if (lane == 0) red[w] = kacc;
    __syncthreads();
    if (tid == 0)
        partials[blockIdx.x] = red[0] + red[1] + red[2] + red[3];
}

__global__ __launch_bounds__(256) void kred(const float* __restrict__ partials, int np,
                                            float* __restrict__ out) {
    __shared__ double red[256];
    double l = 0.0;
    for (int i = threadIdx.x; i < np; i += 256) l += (double)partials[i];
    red[threadIdx.x] = l;
    __syncthreads();
    for (int s = 128; s > 0; s >>= 1) {
        if (threadIdx.x < s) red[threadIdx.x] += red[threadIdx.x + s];
        __syncthreads();
    }
    if (threadIdx.x == 0)
        out[0] = (float)(red[0] * (-0.5 / ((double)NN * (double)NN)));
}

extern "C" void kernel_launch(void* const* d_in, const int* in_sizes, int n_in,
                              void* d_out, int out_size, void* d_ws, size_t ws_size,
                              hipStream_t stream) {
    const float* x  = (const float*)d_in[0];
    const int*   ii = (const int*)d_in[1];
    const int*   ie = (const int*)d_in[2];
    const float* im = (const float*)d_in[3];
    const int*   oi = (const int*)d_in[4];
    const int*   oe = (const int*)d_in[5];
    const float* om = (const float*)d_in[6];
    const float* e1 = (const float*)d_in[7];
    const float* W1 = (const float*)d_in[8];
    const float* b1 = (const float*)d_in[9];
    const float* e2 = (const float*)d_in[10];
    const float* W2 = (const float*)d_in[11];
    const float* b2 = (const float*)d_in[12];
    const float* e3 = (const float*)d_in[13];
    const float* W3 = (const float*)d_in[14];
    const float* b3 = (const float*)d_in[15];
    float* out = (float*)d_out;

    char* ws = (char*)d_ws;
    float*          EW    = (float*)(ws);                     // 3*64*256 f32   (196608 B)
    unsigned short* U1    = (unsigned short*)(ws + 196608);   // 163840 B
    unsigned short* U23   = (unsigned short*)(ws + 360448);   // 327680 B
    float*          parts = (float*)(ws + 688128);            // 1250 f32
    unsigned short* Hc    = (unsigned short*)(ws + 696128);   // 20000*64 bf16  (2.56 MB)
    unsigned short* xh    = (unsigned short*)(ws + 3256128);  // 20000*256 bf16 (10.24 MB)
    unsigned char*  h8    = (unsigned char*)(ws + 13496128);  // 20000*256 fp8  (5.12 MB)

    ewk3  <<<dim3(VV, 3), 256, 0, stream>>>(e1, W1, e2, W2, e3, W3, EW);
    packU2<<<120, 256, 0, stream>>>(W1, EW, W2, EW + VV * DD, W3, EW + 2 * VV * DD, U1, U23);
    prep  <<<NN / 4, 256, 0, stream>>>(ie, im, oe, om, x, Hc, xh);
    fmm1  <<<NN / 16, 256, 0, stream>>>(xh, Hc, ii, im, oi, om, U1, b1, out, h8);
    fmm23 <<<NN / 16, 256, 0, stream>>>(h8, Hc, ii, im, oi, om, U23, b2, b3, parts);
    kred  <<<1, 256, 0, stream>>>(parts, NN / 16, out + (size_t)NN * DD);
}

// Round 7
// 201.963 us; speedup vs baseline: 1.2107x; 1.2107x over previous
//
#include <hip/hip_runtime.h>
#include <math.h>

#define NN 20000
#define KK 16
#define DD 256
#define VV 64
#define NT1 16
#define SAS 336      // fmm1 A-tile row stride in bf16 elems
#define SAS8 336     // fmm23 A-tile row stride in bytes (21*16)

typedef __attribute__((ext_vector_type(8))) __bf16 bf16x8;
typedef __attribute__((ext_vector_type(4))) float floatx4;
typedef __attribute__((ext_vector_type(2))) float floatx2;
typedef __attribute__((ext_vector_type(8))) unsigned short ushort8;

__device__ __forceinline__ float4 ld4(const float* p) { return *reinterpret_cast<const float4*>(p); }

__device__ __forceinline__ unsigned short f2bf(float f) {
    union { float f; unsigned u; } v; v.f = f;
    unsigned r = v.u + 0x7FFFu + ((v.u >> 16) & 1u);
    return (unsigned short)(r >> 16);
}
__device__ __forceinline__ float bf2f(unsigned short u) {
    union { unsigned u; float f; } v; v.u = ((unsigned)u) << 16;
    return v.f;
}
__device__ __forceinline__ unsigned char f2q(float f) {  // fp8 e4m3, RTNE
    return (unsigned char)(__builtin_amdgcn_cvt_pk_fp8_f32(f, 0.f, 0u, false) & 0xFFu);
}
__device__ __forceinline__ float q2f(unsigned char q) {
    floatx2 r = __builtin_amdgcn_cvt_pk_f32_fp8((unsigned)q, false);
    return r.x;
}
__device__ __forceinline__ float ftanh(float v) {
    float e = __expf(2.f * v);
    return 1.f - 2.f * __builtin_amdgcn_rcpf(e + 1.f);
}

// Merged setup: blocks 0..119 pack U1 (bf16) / U23 (fp8) with EW computed inline;
// blocks 120..5119 do edge-histogram (bf16 + fp8) and x -> bf16 cast.
__global__ __launch_bounds__(256) void setup(
    const int* __restrict__ ie, const float* __restrict__ im,
    const int* __restrict__ oe, const float* __restrict__ om,
    const float* __restrict__ x,
    const float* __restrict__ e1, const float* __restrict__ W1,
    const float* __restrict__ e2, const float* __restrict__ W2,
    const float* __restrict__ e3, const float* __restrict__ W3,
    unsigned short* __restrict__ U1, unsigned char* __restrict__ U23,
    unsigned short* __restrict__ Hc, unsigned char* __restrict__ Hc8,
    unsigned short* __restrict__ xh) {
    int blk = blockIdx.x, tid = threadIdx.x;
    if (blk < 120) {
        int u1path = blk < 40;
        int NT = u1path ? 16 : 32;
        int g = (u1path ? blk : blk - 40) * 256 + tid;
        int lane = g & 63, ntk = g >> 6;
        int nt = ntk % NT, kt = ntk / NT;
        if (kt >= 10) return;
        int n = nt * 16 + (lane & 15);
        int kbase = kt * 32 + (lane >> 4) * 8;
        const float* W; const float* emb;
        if (u1path)       { W = W1; emb = e1; }
        else if (n < 256) { W = W2; emb = e2; }
        else              { W = W3; emb = e3; n -= 256; }
        float vals[8];
        if (kbase < 256) {
            #pragma unroll
            for (int j = 0; j < 8; ++j) vals[j] = W[(size_t)(kbase + j) * DD + n];
        } else {
            int vb = kbase - 256;  // 8 consecutive edge-vocab rows; EW inline
            #pragma unroll
            for (int z = 0; z < 8; ++z) vals[z] = 0.f;
            #pragma unroll 4
            for (int j = 0; j < 256; ++j) {
                float wv = W[(size_t)(256 + j) * DD + n];
                #pragma unroll
                for (int z = 0; z < 8; ++z) vals[z] += emb[(vb + z) * DD + j] * wv;
            }
        }
        if (u1path) {
            unsigned short o8[8];
            #pragma unroll
            for (int j = 0; j < 8; ++j) o8[j] = f2bf(vals[j]);
            *reinterpret_cast<uint4*>(&U1[(size_t)g * 8]) = *reinterpret_cast<uint4*>(o8);
        } else {
            unsigned char o8[8];
            #pragma unroll
            for (int j = 0; j < 8; ++j) o8[j] = f2q(vals[j]);
            *reinterpret_cast<uint2*>(&U23[(size_t)g * 8]) = *reinterpret_cast<uint2*>(o8);
        }
    } else {
        int pb = blk - 120;
        int w = tid >> 6, lane = tid & 63;
        int n = pb * 4 + w;
        int e = 0; float m = 0.f;
        if (lane < 16)      { e = ie[n * KK + lane];      m = im[n * KK + lane]; }
        else if (lane < 32) { e = oe[n * KK + lane - 16]; m = om[n * KK + lane - 16]; }
        float h = 0.f;
        #pragma unroll
        for (int j = 0; j < 32; ++j) {
            int ev = __shfl(e, j);
            float mv = __shfl(m, j);
            if (ev == lane) h += mv;
        }
        Hc [(size_t)n * 64 + lane] = f2bf(h);
        Hc8[(size_t)n * 64 + lane] = f2q(h);
        size_t base = (size_t)pb * 1024 + tid * 4;
        float4 v = ld4(x + base);
        ushort4 o; o.x = f2bf(v.x); o.y = f2bf(v.y); o.z = f2bf(v.z); o.w = f2bf(v.w);
        *reinterpret_cast<ushort4*>(xh + base) = o;
    }
}

// Fused pass 1 (R5-proven gather scheme): bf16 gather of x into LDS A-tile, then
// hidden = x + 2*b1 + [S1|H] @ U1. Writes f32 out + fp8 copy for the KLD path.
__global__ __launch_bounds__(256) void fmm1(const unsigned short* __restrict__ xh, const unsigned short* __restrict__ Hc,
                                            const int* __restrict__ ii, const float* __restrict__ im,
                                            const int* __restrict__ oi, const float* __restrict__ om,
                                            const unsigned short* __restrict__ U, const float* __restrict__ b,
                                            float* __restrict__ out, unsigned char* __restrict__ h8) {
    __shared__ unsigned short sA[16 * SAS];
    __shared__ int sidx[16][32];
    __shared__ float smsk[16][32];
    int n0 = blockIdx.x * 16;
    int tid = threadIdx.x;
    for (int q = tid; q < 512; q += 256) {
        int r = q >> 5, j = q & 31;
        int n = n0 + r;
        sidx[r][j] = (j < 16) ? ii[n * KK + j] : oi[n * KK + j - 16];
        smsk[r][j] = (j < 16) ? im[n * KK + j] : om[n * KK + j - 16];
    }
    if (tid < 128) {  // stage H cols [256,320)
        int r = tid >> 3, k8 = tid & 7;
        *reinterpret_cast<uint4*>(&sA[r * SAS + 256 + k8 * 8]) =
            *reinterpret_cast<const uint4*>(&Hc[(size_t)(n0 + r) * 64 + k8 * 8]);
    }
    __syncthreads();
    int lane = tid & 63, w = tid >> 6;
    int half = lane >> 5, c = (lane & 31) * 8;
    #pragma unroll
    for (int rr = 0; rr < 4; ++rr) {
        int row = w * 4 + rr;
        float acc[8] = {0.f, 0.f, 0.f, 0.f, 0.f, 0.f, 0.f, 0.f};
        #pragma unroll
        for (int j = 0; j < 16; ++j) {
            int j2 = j * 2 + half;
            int idx = sidx[row][j2];
            float m = smsk[row][j2];
            ushort8 u = *reinterpret_cast<const ushort8*>(xh + (size_t)idx * DD + c);
            #pragma unroll
            for (int z = 0; z < 8; ++z) acc[z] += m * bf2f(u[z]);
        }
        #pragma unroll
        for (int z = 0; z < 8; ++z) acc[z] += __shfl_xor(acc[z], 32);
        if (half == 0) {
            unsigned short o8[8];
            #pragma unroll
            for (int z = 0; z < 8; ++z) o8[z] = f2bf(acc[z]);
            *reinterpret_cast<uint4*>(&sA[row * SAS + c]) = *reinterpret_cast<uint4*>(o8);
        }
    }
    __syncthreads();
    int lr = lane & 15, quad = lane >> 4;
    float xp[4][4], bb[4];
    #pragma unroll
    for (int t = 0; t < 4; ++t) {
        int col = (w * 4 + t) * 16 + lr;
        bb[t] = 2.f * b[col];
        #pragma unroll
        for (int r = 0; r < 4; ++r)
            xp[t][r] = bf2f(xh[(size_t)(n0 + quad * 4 + r) * DD + col]);
    }
    floatx4 z = {0.f, 0.f, 0.f, 0.f};
    floatx4 acc[4] = {z, z, z, z};
    for (int kt = 0; kt < 10; ++kt) {
        bf16x8 a = *reinterpret_cast<const bf16x8*>(&sA[lr * SAS + kt * 32 + quad * 8]);
        #pragma unroll
        for (int t = 0; t < 4; ++t) {
            bf16x8 bf = *reinterpret_cast<const bf16x8*>(&U[(size_t)((kt * NT1 + w * 4 + t) * 64 + lane) * 8]);
            acc[t] = __builtin_amdgcn_mfma_f32_16x16x32_bf16(a, bf, acc[t], 0, 0, 0);
        }
    }
    #pragma unroll
    for (int t = 0; t < 4; ++t) {
        int col = (w * 4 + t) * 16 + lr;
        #pragma unroll
        for (int r = 0; r < 4; ++r) {
            size_t o = (size_t)(n0 + quad * 4 + r) * DD + col;
            float v = xp[t][r] + bb[t] + acc[t][r];
            out[o] = v;
            h8[o] = f2q(v);
        }
    }
}

// Fused pass 2, all-fp8 GEMM: fp8 gather of hidden into fp8 LDS A-tile, then BOTH
// mu and logvar via mfma fp8_fp8 + fast tanh + KLD partial atomically accumulated.
__global__ __launch_bounds__(256) void fmm23(const unsigned char* __restrict__ h8, const unsigned char* __restrict__ Hc8,
                                             const int* __restrict__ ii, const float* __restrict__ im,
                                             const int* __restrict__ oi, const float* __restrict__ om,
                                             const unsigned char* __restrict__ U, const float* __restrict__ b2,
                                             const float* __restrict__ b3, float* __restrict__ kld) {
    __shared__ unsigned char sA[16 * SAS8];
    __shared__ int sidx[16][32];
    __shared__ float smsk[16][32];
    __shared__ float red[4];
    int n0 = blockIdx.x * 16;
    int tid = threadIdx.x;
    for (int q = tid; q < 512; q += 256) {
        int r = q >> 5, j = q & 31;
        int n = n0 + r;
        sidx[r][j] = (j < 16) ? ii[n * KK + j] : oi[n * KK + j - 16];
        smsk[r][j] = (j < 16) ? im[n * KK + j] : om[n * KK + j - 16];
    }
    if (tid < 128) {  // stage fp8 H cols [256,320): 8B per thread
        int r = tid >> 3, k8 = tid & 7;
        *reinterpret_cast<uint2*>(&sA[r * SAS8 + 256 + k8 * 8]) =
            *reinterpret_cast<const uint2*>(&Hc8[(size_t)(n0 + r) * 64 + k8 * 8]);
    }
    __syncthreads();
    int lane = tid & 63, w = tid >> 6;
    int g = lane >> 4, cl = lane & 15;
    #pragma unroll
    for (int rr = 0; rr < 4; ++rr) {
        int row = w * 4 + rr;
        float acc[16];
        #pragma unroll
        for (int z = 0; z < 16; ++z) acc[z] = 0.f;
        #pragma unroll
        for (int j = 0; j < 8; ++j) {
            int r = g * 8 + j;
            int idx = sidx[row][r];
            float m = smsk[row][r];
            uint4 u = *reinterpret_cast<const uint4*>(h8 + (size_t)idx * DD + cl * 16);
            unsigned dw[4] = {u.x, u.y, u.z, u.w};
            #pragma unroll
            for (int d = 0; d < 4; ++d) {
                floatx2 f01 = __builtin_amdgcn_cvt_pk_f32_fp8(dw[d], false);
                floatx2 f23 = __builtin_amdgcn_cvt_pk_f32_fp8(dw[d], true);
                acc[d * 4 + 0] += m * f01.x; acc[d * 4 + 1] += m * f01.y;
                acc[d * 4 + 2] += m * f23.x; acc[d * 4 + 3] += m * f23.y;
            }
        }
        #pragma unroll
        for (int z = 0; z < 16; ++z) {
            acc[z] += __shfl_xor(acc[z], 16);
            acc[z] += __shfl_xor(acc[z], 32);
        }
        if (g == 0) {
            unsigned char o16[16];
            #pragma unroll
            for (int z = 0; z < 16; ++z) o16[z] = f2q(acc[z]);
            *reinterpret_cast<uint4*>(&sA[row * SAS8 + cl * 16]) = *reinterpret_cast<uint4*>(o16);
        }
    }
    __syncthreads();
    int lr = lane & 15, quad = lane >> 4;
    float hp[4][4], bm[4], bl[4];
    #pragma unroll
    for (int t = 0; t < 4; ++t) {
        int col = (w * 4 + t) * 16 + lr;
        bm[t] = 2.f * b2[col];
        bl[t] = 2.f * b3[col];
        #pragma unroll
        for (int r = 0; r < 4; ++r)
            hp[t][r] = q2f(h8[(size_t)(n0 + quad * 4 + r) * DD + col]);
    }
    floatx4 z = {0.f, 0.f, 0.f, 0.f};
    floatx4 am[4] = {z, z, z, z};
    floatx4 al[4] = {z, z, z, z};
    for (int kt = 0; kt < 10; ++kt) {
        long a = *reinterpret_cast<const long*>(&sA[lr * SAS8 + kt * 32 + quad * 8]);
        #pragma unroll
        for (int t = 0; t < 4; ++t) {
            int nt = w * 4 + t;
            long bmu = *reinterpret_cast<const long*>(&U[(size_t)((kt * 32 + nt) * 64 + lane) * 8]);
            long blv = *reinterpret_cast<const long*>(&U[(size_t)((kt * 32 + 16 + nt) * 64 + lane) * 8]);
            am[t] = __builtin_amdgcn_mfma_f32_16x16x32_fp8_fp8(a, bmu, am[t], 0, 0, 0);
            al[t] = __builtin_amdgcn_mfma_f32_16x16x32_fp8_fp8(a, blv, al[t], 0, 0, 0);
        }
    }
    float kacc = 0.f;
    #pragma unroll
    for (int t = 0; t < 4; ++t) {
        #pragma unroll
        for (int r = 0; r < 4; ++r) {
            float h = hp[t][r];
            float tm = ftanh(h + bm[t] + am[t][r]);
            float tl = ftanh(h + bl[t] + al[t][r]);
            kacc += (1.f - tm * tm) + (2.f * tl - __expf(2.f * tl));
        }
    }
    #pragma unroll
    for (int off = 32; off > 0; off >>= 1) kacc += __shfl_xor(kacc, off);
    if (lane == 0) red[w] = kacc;
    __syncthreads();
    if (tid == 0)
        atomicAdd(kld, (red[0] + red[1] + red[2] + red[3]) * (-0.5f / ((float)NN * (float)NN)));
}

extern "C" void kernel_launch(void* const* d_in, const int* in_sizes, int n_in,
                              void* d_out, int out_size, void* d_ws, size_t ws_size,
                              hipStream_t stream) {
    const float* x  = (const float*)d_in[0];
    const int*   ii = (const int*)d_in[1];
    const int*   ie = (const int*)d_in[2];
    const float* im = (const float*)d_in[3];
    const int*   oi = (const int*)d_in[4];
    const int*   oe = (const int*)d_in[5];
    const float* om = (const float*)d_in[6];
    const float* e1 = (const float*)d_in[7];
    const float* W1 = (const float*)d_in[8];
    const float* b1 = (const float*)d_in[9];
    const float* e2 = (const float*)d_in[10];
    const float* W2 = (const float*)d_in[11];
    const float* b2 = (const float*)d_in[12];
    const float* e3 = (const float*)d_in[13];
    const float* W3 = (const float*)d_in[14];
    const float* b3 = (const float*)d_in[15];
    float* out = (float*)d_out;

    char* ws = (char*)d_ws;
    unsigned short* U1  = (unsigned short*)(ws);             // 10*16*64*8 bf16 (163840 B)
    unsigned char*  U23 = (unsigned char*)(ws + 163840);     // 10*32*64*8 fp8  (163840 B)
    unsigned short* Hc  = (unsigned short*)(ws + 327680);    // 20000*64 bf16   (2.56 MB)
    unsigned char*  Hc8 = (unsigned char*)(ws + 2887680);    // 20000*64 fp8    (1.28 MB)
    unsigned short* xh  = (unsigned short*)(ws + 4167680);   // 20000*256 bf16  (10.24 MB)
    unsigned char*  h8  = (unsigned char*)(ws + 14407680);   // 20000*256 fp8   (5.12 MB)

    hipMemsetAsync(out + (size_t)NN * DD, 0, 4, stream);     // zero kld accumulator
    setup<<<120 + NN / 4, 256, 0, stream>>>(ie, im, oe, om, x, e1, W1, e2, W2, e3, W3,
                                            U1, U23, Hc, Hc8, xh);
    fmm1 <<<NN / 16, 256, 0, stream>>>(xh, Hc, ii, im, oi, om, U1, b1, out, h8);
    fmm23<<<NN / 16, 256, 0, stream>>>(h8, Hc8, ii, im, oi, om, U23, b2, b3,
                                       out + (size_t)NN * DD);
}